// Round 8
// baseline (140.548 us; speedup 1.0000x reference)
//
#include <hip/hip_runtime.h>
#include <hip/hip_bf16.h>
#include <stdint.h>

#define S_SCALE 30.0f
#define S_LOG2E 43.2808512266689f   /* 30 * log2(e) */
#define N_ROWS 8192
#define D_DIM 256
#define C_CLS 10000
#define NCB 8

typedef __attribute__((ext_vector_type(8))) short short8;
typedef __attribute__((ext_vector_type(4))) float f32x4;
typedef __attribute__((ext_vector_type(4))) unsigned short us4;

static __device__ __forceinline__ unsigned short f2bf(float f) {
  union { float f; unsigned u; } a; a.f = f;
  unsigned r = a.u + 0x7fffu + ((a.u >> 16) & 1u);
  return (unsigned short)(r >> 16);
}

static __device__ __forceinline__ void gl16(const void* g, void* l) {
  __builtin_amdgcn_global_load_lds(
      (const __attribute__((address_space(1))) void*)g,
      (__attribute__((address_space(3))) void*)l, 16, 0, 0);
}

// 16-lane (DPP-row) sum, VALU pipe only; all lanes receive the group sum.
static __device__ __forceinline__ float row_sum16(float v) {
  union { float f; int i; } u, w;
  u.f = v;
  w.i = __builtin_amdgcn_update_dpp(0, u.i, 0xB1, 0xF, 0xF, true);  u.f += w.f; // lane^1
  w.i = __builtin_amdgcn_update_dpp(0, u.i, 0x4E, 0xF, 0xF, true);  u.f += w.f; // lane^2
  w.i = __builtin_amdgcn_update_dpp(0, u.i, 0x141, 0xF, 0xF, true); u.f += w.f; // half-mirror
  w.i = __builtin_amdgcn_update_dpp(0, u.i, 0x140, 0xF, 0xF, true); u.f += w.f; // row-mirror
  return u.f;
}

// ------- fused: row L2-normalize -> bf16 (row-major), exact fp32 target logit ----
__global__ __launch_bounds__(256) void k_normtgt(const float* __restrict__ x,
                                                 const float* __restrict__ W,
                                                 const int* __restrict__ target,
                                                 unsigned short* __restrict__ xnb,
                                                 float* __restrict__ tgt) {
  int row = blockIdx.x * 4 + (threadIdx.x >> 6);
  int l = threadIdx.x & 63;
  const float4 v = *(const float4*)(x + (size_t)row * D_DIM + l * 4);
  float ss = v.x * v.x + v.y * v.y + v.z * v.z + v.w * v.w;
#pragma unroll
  for (int m = 1; m < 64; m <<= 1) ss += __shfl_xor(ss, m, 64);
  float rn = 1.0f / sqrtf(ss);
  us4 o;
  o.x = f2bf(v.x * rn); o.y = f2bf(v.y * rn);
  o.z = f2bf(v.z * rn); o.w = f2bf(v.w * rn);
  *(us4*)(xnb + (size_t)row * D_DIM + l * 4) = o;
  int tc = target[row];
  const float4 b = *(const float4*)(W + (size_t)tc * D_DIM + l * 4);
  float s = v.x * b.x + v.y * b.y + v.z * b.z + v.w * b.w;
#pragma unroll
  for (int m = 1; m < 64; m <<= 1) s += __shfl_xor(s, m, 64);
  if (l == 0) tgt[row] = s * rn;
}

// ---- W fp32 -> bf16 in MFMA-FRAGMENT layout: [c16 0..639][kc 0..7][lane]16B ----
// lane = lk*16+lr holds W[col = c16*16+lr][k = kc*32+lk*8 .. +8]; cols>=C zero.
__global__ __launch_bounds__(256) void k_convw(const float* __restrict__ W,
                                               unsigned short* __restrict__ WbF) {
  int gidx = blockIdx.x * 256 + threadIdx.x;   // 0..327679 = 640*8*64
  int lane = gidx & 63;
  int kc = (gidx >> 6) & 7;
  int c16 = gidx >> 9;
  int col = c16 * 16 + (lane & 15);
  int k0 = kc * 32 + (lane >> 4) * 8;
  us4 o0 = {0, 0, 0, 0}, o1 = {0, 0, 0, 0};
  if (col < C_CLS) {
    const float4 a = *(const float4*)(W + (size_t)col * D_DIM + k0);
    const float4 b = *(const float4*)(W + (size_t)col * D_DIM + k0 + 4);
    o0.x = f2bf(a.x); o0.y = f2bf(a.y); o0.z = f2bf(a.z); o0.w = f2bf(a.w);
    o1.x = f2bf(b.x); o1.y = f2bf(b.y); o1.z = f2bf(b.z); o1.w = f2bf(b.w);
  }
  *(us4*)(WbF + (size_t)gidx * 8) = o0;
  *(us4*)(WbF + (size_t)gidx * 8 + 4) = o1;
}

// ------- barrier-free fused bf16 GEMM + exp-sum epilogue -------
// 256 blocks (1/CU), fixed br; A panel (256x256 = 128 KB) staged ONCE into
// frag-layout LDS (lane-linear ds_read_b128, conflict-free, no swizzle).
// B read per-fragment from frag-layout global (1 KB coalesced dwordx4, L2-hit),
// double-buffered in registers one kc ahead. NO barriers in the hot loop.
// Epilogue per bc-tile: pure-VALU exp2 into 32 reg accumulators; one DPP
// reduce + one LDS round + coalesced store at the very end.
__global__ __launch_bounds__(512, 2) void k_gemm(const unsigned short* __restrict__ xnb,
                                                 const unsigned short* __restrict__ WbF,
                                                 float* __restrict__ partials) {
  __shared__ __align__(16) char lds[135168];   // A frags 128 KB @0; rowsum 4 KB @131072
  const int b = blockIdx.x;
  const int x8 = b & 7, q = b >> 3;
  const int br = (x8 >> 2) * 16 + (q & 15);          // fixed A panel
  const int bc0 = (x8 & 3) * 10 + (q >> 4) * 5;      // 5 consecutive bc tiles
  const int cc = (x8 & 3) * 2 + (q >> 4);            // 0..7 partial-chunk id
  const int t = threadIdx.x;
  const int w = t >> 6, l = t & 63;
  const int wr = w >> 2, wc = w & 3;                 // 2M x 4N waves (128x64 tile)
  const int lr = l & 15, lk = l >> 4;

  // ---- stage A panel once: slot(r16l 0..15, kc 0..7) = 1 KB lane-linear ----
  {
    const char* AgL = (const char*)xnb + (size_t)br * 256 * 512 + (size_t)lr * 512 + lk * 16;
#pragma unroll
    for (int i = 0; i < 16; ++i) {
      int slot = w * 16 + i;                  // 128 slots
      int r16l = slot >> 3, kc = slot & 7;
      gl16(AgL + (size_t)r16l * 8192 + kc * 64, lds + slot * 1024);
    }
    asm volatile("s_waitcnt vmcnt(0)" ::: "memory");
    __builtin_amdgcn_sched_barrier(0);
    __builtin_amdgcn_s_barrier();
  }

  f32x4 acc[8][4];
#pragma unroll
  for (int m = 0; m < 8; m++)
#pragma unroll
    for (int n = 0; n < 4; n++) acc[m][n] = (f32x4){0.f, 0.f, 0.f, 0.f};
  float rsacc[8][4];
#pragma unroll
  for (int m = 0; m < 8; m++)
#pragma unroll
    for (int j = 0; j < 4; j++) rsacc[m][j] = 0.f;

  // wave's A base in LDS (slot = (wr*8+fm)*8 + kc), per-lane
  const char* AwL = lds + (size_t)(wr * 8) * 8192 + (size_t)l * 16;
  // wave's B base in global frag layout, per-lane
  const char* Bw = (const char*)WbF + ((size_t)(bc0 * 16 + wc * 4) * 8) * 1024 + (size_t)l * 16;

  for (int tt = 0; tt < 5; ++tt) {
    short8 b0[4], b1[4];
#pragma unroll
    for (int fn = 0; fn < 4; ++fn) b0[fn] = *(const short8*)(Bw + fn * 8192);

    auto step = [&](int kc, short8(&cur)[4], short8(&nxt)[4]) {
      if (kc < 7) {
#pragma unroll
        for (int fn = 0; fn < 4; ++fn)
          nxt[fn] = *(const short8*)(Bw + fn * 8192 + (kc + 1) * 1024);
      }
      short8 a[8];
#pragma unroll
      for (int fm = 0; fm < 8; ++fm)
        a[fm] = *(const short8*)(AwL + (fm * 8 + kc) * 1024);
#pragma unroll
      for (int fm = 0; fm < 8; ++fm)
#pragma unroll
        for (int fn = 0; fn < 4; ++fn)
          acc[fm][fn] = __builtin_amdgcn_mfma_f32_16x16x32_bf16(a[fm], cur[fn], acc[fm][fn], 0, 0, 0);
    };
    step(0, b0, b1); step(1, b1, b0); step(2, b0, b1); step(3, b1, b0);
    step(4, b0, b1); step(5, b1, b0); step(6, b0, b1); step(7, b1, b0);

    // ---- per-bc-tile epilogue: pure VALU exp2 accumulate, zero acc ----
    // 16x16 C/D: col = lane&15, row = (lane>>4)*4 + j.
    const int bc = bc0 + tt;
#pragma unroll
    for (int m = 0; m < 8; ++m) {
#pragma unroll
      for (int n = 0; n < 4; ++n) {
        int col = bc * 256 + wc * 64 + n * 16 + lr;
        bool ok = (col < C_CLS);
#pragma unroll
        for (int j = 0; j < 4; ++j)
          rsacc[m][j] += ok ? __builtin_amdgcn_exp2f(acc[m][n][j] * S_LOG2E) : 0.f;
        acc[m][n] = (f32x4){0.f, 0.f, 0.f, 0.f};
      }
    }
    Bw += 131072;   // next bc tile (16 colblks * 8 kc * 1024 B)
  }

  // ---- final: DPP 16-lane reduce, one LDS round, one coalesced store ----
  float* rsum = (float*)(lds + 131072);   // [4 wc][256 rows]
#pragma unroll
  for (int m = 0; m < 8; ++m)
#pragma unroll
    for (int j = 0; j < 4; ++j) rsacc[m][j] = row_sum16(rsacc[m][j]);
  if (lr == 0) {
#pragma unroll
    for (int m = 0; m < 8; ++m)
#pragma unroll
      for (int j = 0; j < 4; ++j)
        rsum[wc * 256 + wr * 128 + m * 16 + lk * 4 + j] = rsacc[m][j];
  }
  __syncthreads();
  if (t < 256) {
    float sv = rsum[t] + rsum[256 + t] + rsum[512 + t] + rsum[768 + t];
    partials[(size_t)cc * N_ROWS + (size_t)br * 256 + t] = sv;
  }
}

// ---------------- per-row loss + block partial sums ----------------
__global__ __launch_bounds__(256) void k_loss1(const float* __restrict__ partials,
                                               const float* __restrict__ tgt,
                                               float* __restrict__ bsum) {
  __shared__ float wsum[4];
  int i = blockIdx.x * 256 + threadIdx.x;
  const float* p = partials + i;
  float s = 0.f;
#pragma unroll
  for (int j = 0; j < NCB; ++j) s += p[(size_t)j * N_ROWS];
  float tl = tgt[i];
  float tcv = fminf(fmaxf(tl, -1.0f + 1e-7f), 1.0f - 1e-7f);
  const float cm = 0.95533648912560601964f;   // cos(0.3)
  const float sm = 0.29552020666133957510f;   // sin(0.3)
  float num = S_SCALE * (tcv * cm - sqrtf(fmaxf(1.0f - tcv * tcv, 0.f)) * sm);
  float sum_excl = s - __expf(S_SCALE * tl);
  float denom = __expf(num) + sum_excl;
  float L = num - __logf(denom);
#pragma unroll
  for (int m = 1; m < 64; m <<= 1) L += __shfl_xor(L, m, 64);
  int l = threadIdx.x & 63, w = threadIdx.x >> 6;
  if (l == 0) wsum[w] = L;
  __syncthreads();
  if (threadIdx.x == 0) bsum[blockIdx.x] = wsum[0] + wsum[1] + wsum[2] + wsum[3];
}

__global__ void k_loss2(const float* __restrict__ bsum, float* __restrict__ out) {
  float s = 0.f;
  for (int i = 0; i < 32; ++i) s += bsum[i];
  out[0] = -s / (float)N_ROWS;
}

// ---------------- launch ----------------
extern "C" void kernel_launch(void* const* d_in, const int* in_sizes, int n_in,
                              void* d_out, int out_size, void* d_ws, size_t ws_size,
                              hipStream_t stream) {
  const float* x = (const float*)d_in[0];
  const float* W = (const float*)d_in[1];
  const int* target = (const int*)d_in[2];
  float* out = (float*)d_out;
  char* ws = (char*)d_ws;

  unsigned short* xnb = (unsigned short*)(ws);              // 8192*256*2   = 4,194,304
  unsigned short* WbF = (unsigned short*)(ws + 4194304);    // 640*8*1024   = 5,242,880
  float* tgt = (float*)(ws + 9437184);                      // 8192*4
  float* partials = (float*)(ws + 9469952);                 // 8*8192*4     = 262,144
  float* bsum = (float*)(ws + 9732096);                     // 32*4

  k_normtgt<<<2048, 256, 0, stream>>>(x, W, target, xnb, tgt);
  k_convw<<<1280, 256, 0, stream>>>(W, WbF);
  k_gemm<<<256, 512, 0, stream>>>(xnb, WbF, partials);
  k_loss1<<<32, 256, 0, stream>>>(partials, tgt, bsum);
  k_loss2<<<1, 1, 0, stream>>>(bsum, out);
}

// Round 9
// 61.977 us; speedup vs baseline: 2.2677x; 2.2677x over previous
//
#include <hip/hip_runtime.h>
#include <hip/hip_bf16.h>
#include <stdint.h>

#define S_SCALE 30.0f
#define S_LOG2E 43.2808512266689f   /* 30 * log2(e) */
#define N_ROWS 8192
#define D_DIM 256
#define C_CLS 10000
#define NCB 8

typedef __attribute__((ext_vector_type(8))) short short8;
typedef __attribute__((ext_vector_type(4))) float f32x4;
typedef __attribute__((ext_vector_type(4))) unsigned short us4;

static __device__ __forceinline__ unsigned short f2bf(float f) {
  union { float f; unsigned u; } a; a.f = f;
  unsigned r = a.u + 0x7fffu + ((a.u >> 16) & 1u);
  return (unsigned short)(r >> 16);
}

static __device__ __forceinline__ void gl16(const void* g, void* l) {
  __builtin_amdgcn_global_load_lds(
      (const __attribute__((address_space(1))) void*)g,
      (__attribute__((address_space(3))) void*)l, 16, 0, 0);
}

// 16-lane (DPP-row) sum, VALU pipe only; all lanes receive the group sum.
static __device__ __forceinline__ float row_sum16(float v) {
  union { float f; int i; } u, w;
  u.f = v;
  w.i = __builtin_amdgcn_update_dpp(0, u.i, 0xB1, 0xF, 0xF, true);  u.f += w.f; // lane^1
  w.i = __builtin_amdgcn_update_dpp(0, u.i, 0x4E, 0xF, 0xF, true);  u.f += w.f; // lane^2
  w.i = __builtin_amdgcn_update_dpp(0, u.i, 0x141, 0xF, 0xF, true); u.f += w.f; // half-mirror
  w.i = __builtin_amdgcn_update_dpp(0, u.i, 0x140, 0xF, 0xF, true); u.f += w.f; // row-mirror
  return u.f;
}

// ------- fused: row L2-normalize -> bf16 (row-major), exact fp32 target logit ----
__global__ __launch_bounds__(256) void k_normtgt(const float* __restrict__ x,
                                                 const float* __restrict__ W,
                                                 const int* __restrict__ target,
                                                 unsigned short* __restrict__ xnb,
                                                 float* __restrict__ tgt) {
  int row = blockIdx.x * 4 + (threadIdx.x >> 6);
  int l = threadIdx.x & 63;
  const float4 v = *(const float4*)(x + (size_t)row * D_DIM + l * 4);
  float ss = v.x * v.x + v.y * v.y + v.z * v.z + v.w * v.w;
#pragma unroll
  for (int m = 1; m < 64; m <<= 1) ss += __shfl_xor(ss, m, 64);
  float rn = 1.0f / sqrtf(ss);
  us4 o;
  o.x = f2bf(v.x * rn); o.y = f2bf(v.y * rn);
  o.z = f2bf(v.z * rn); o.w = f2bf(v.w * rn);
  *(us4*)(xnb + (size_t)row * D_DIM + l * 4) = o;
  int tc = target[row];
  const float4 b = *(const float4*)(W + (size_t)tc * D_DIM + l * 4);
  float s = v.x * b.x + v.y * b.y + v.z * b.z + v.w * b.w;
#pragma unroll
  for (int m = 1; m < 64; m <<= 1) s += __shfl_xor(s, m, 64);
  if (l == 0) tgt[row] = s * rn;
}

// ---- W fp32 -> bf16 in MFMA-FRAGMENT layout: [c16 0..639][kc 0..7][lane]16B ----
// lane = lk*16+lr holds W[col = c16*16+lr][k = kc*32+lk*8 .. +8]; cols>=C zero.
__global__ __launch_bounds__(256) void k_convw(const float* __restrict__ W,
                                               unsigned short* __restrict__ WbF) {
  int gidx = blockIdx.x * 256 + threadIdx.x;   // 0..327679 = 640*8*64
  int lane = gidx & 63;
  int kc = (gidx >> 6) & 7;
  int c16 = gidx >> 9;
  int col = c16 * 16 + (lane & 15);
  int k0 = kc * 32 + (lane >> 4) * 8;
  us4 o0 = {0, 0, 0, 0}, o1 = {0, 0, 0, 0};
  if (col < C_CLS) {
    const float4 a = *(const float4*)(W + (size_t)col * D_DIM + k0);
    const float4 b = *(const float4*)(W + (size_t)col * D_DIM + k0 + 4);
    o0.x = f2bf(a.x); o0.y = f2bf(a.y); o0.z = f2bf(a.z); o0.w = f2bf(a.w);
    o1.x = f2bf(b.x); o1.y = f2bf(b.y); o1.z = f2bf(b.z); o1.w = f2bf(b.w);
  }
  *(us4*)(WbF + (size_t)gidx * 8) = o0;
  *(us4*)(WbF + (size_t)gidx * 8 + 4) = o1;
}

// ------- barrier-free fused bf16 GEMM + exp-sum epilogue (low-reg version) -------
// 256 blocks (1/CU), fixed br; A panel (256x256 = 128 KB) staged ONCE into
// frag-layout LDS (lane-linear ds_read_b128, conflict-free). B streamed from
// frag-layout global (coalesced 1 KB dwordx4, L2-hit), single prefetch buffer.
// Register budget kept < 256: A frags loaded 2-at-a-time; per-tile exp-sums
// DPP-reduced immediately and accumulated in per-wave private LDS rows.
__global__ __launch_bounds__(512, 2) void k_gemm(const unsigned short* __restrict__ xnb,
                                                 const unsigned short* __restrict__ WbF,
                                                 float* __restrict__ partials) {
  __shared__ __align__(16) char lds[135168];   // A frags 128 KB @0; rsum 4 KB @131072
  const int b = blockIdx.x;
  const int x8 = b & 7, q = b >> 3;
  const int br = (x8 >> 2) * 16 + (q & 15);          // fixed A panel
  const int bc0 = ((x8 & 3) * 2 + (q >> 4)) * 5;     // 5 consecutive bc tiles
  const int cc = (x8 & 3) * 2 + (q >> 4);            // 0..7 partial-chunk id
  const int t = threadIdx.x;
  const int w = t >> 6, l = t & 63;
  const int wr = w >> 2, wc = w & 3;                 // 2M x 4N waves (128x64 tile)
  const int lr = l & 15, lk = l >> 4;
  float* rsumAll = (float*)(lds + 131072);           // [8 waves][128 rows]

  // zero per-wave accumulation rows (covered by the staging barrier below)
  if (t < 512) ((float2*)rsumAll)[t] = (float2){0.f, 0.f};

  // ---- stage A panel once: slot(r16l 0..15, kc 0..7) = 1 KB lane-linear ----
  {
    const char* AgL = (const char*)xnb + (size_t)br * 256 * 512 + (size_t)lr * 512 + lk * 16;
#pragma unroll
    for (int i = 0; i < 16; ++i) {
      int slot = w * 16 + i;                  // 128 slots
      int r16l = slot >> 3, kc = slot & 7;
      gl16(AgL + (size_t)r16l * 8192 + kc * 64, lds + slot * 1024);
    }
    asm volatile("s_waitcnt vmcnt(0)" ::: "memory");
    __builtin_amdgcn_sched_barrier(0);
    __builtin_amdgcn_s_barrier();
  }

  f32x4 acc[8][4];
#pragma unroll
  for (int m = 0; m < 8; m++)
#pragma unroll
    for (int n = 0; n < 4; n++) acc[m][n] = (f32x4){0.f, 0.f, 0.f, 0.f};

  // wave's A base in LDS (slot = (wr*8+fm)*8 + kc), per-lane
  const char* AwL = lds + (size_t)(wr * 8) * 8192 + (size_t)l * 16;
  // wave's B base in global frag layout, per-lane
  const char* Bw = (const char*)WbF + ((size_t)(bc0 * 16 + wc * 4) * 8) * 1024 + (size_t)l * 16;
  float* rw = rsumAll + w * 128;                     // this wave's private rows

  for (int tt = 0; tt < 5; ++tt) {
    short8 b0[4], b1[4];
#pragma unroll
    for (int fn = 0; fn < 4; ++fn) b0[fn] = *(const short8*)(Bw + fn * 8192);

    auto step = [&](int kc, short8(&cur)[4], short8(&nxt)[4]) {
      if (kc < 7) {
#pragma unroll
        for (int fn = 0; fn < 4; ++fn)
          nxt[fn] = *(const short8*)(Bw + fn * 8192 + (kc + 1) * 1024);
      }
#pragma unroll
      for (int fm2 = 0; fm2 < 4; ++fm2) {
        short8 a0 = *(const short8*)(AwL + ((2 * fm2) * 8 + kc) * 1024);
        short8 a1 = *(const short8*)(AwL + ((2 * fm2 + 1) * 8 + kc) * 1024);
#pragma unroll
        for (int fn = 0; fn < 4; ++fn)
          acc[2 * fm2][fn] = __builtin_amdgcn_mfma_f32_16x16x32_bf16(a0, cur[fn], acc[2 * fm2][fn], 0, 0, 0);
#pragma unroll
        for (int fn = 0; fn < 4; ++fn)
          acc[2 * fm2 + 1][fn] = __builtin_amdgcn_mfma_f32_16x16x32_bf16(a1, cur[fn], acc[2 * fm2 + 1][fn], 0, 0, 0);
      }
    };
    step(0, b0, b1); step(1, b1, b0); step(2, b0, b1); step(3, b1, b0);
    step(4, b0, b1); step(5, b1, b0); step(6, b0, b1); step(7, b1, b0);

    // ---- per-tile epilogue: exp2, DPP col-reduce, accumulate into LDS rows ----
    // 16x16 C/D: col = lane&15, row = (lane>>4)*4 + j.
    const int bc = bc0 + tt;
#pragma unroll
    for (int m = 0; m < 8; ++m) {
      float rs0 = 0.f, rs1 = 0.f, rs2 = 0.f, rs3 = 0.f;
#pragma unroll
      for (int n = 0; n < 4; ++n) {
        int col = bc * 256 + wc * 64 + n * 16 + lr;
        bool ok = (col < C_CLS);
        rs0 += ok ? __builtin_amdgcn_exp2f(acc[m][n][0] * S_LOG2E) : 0.f;
        rs1 += ok ? __builtin_amdgcn_exp2f(acc[m][n][1] * S_LOG2E) : 0.f;
        rs2 += ok ? __builtin_amdgcn_exp2f(acc[m][n][2] * S_LOG2E) : 0.f;
        rs3 += ok ? __builtin_amdgcn_exp2f(acc[m][n][3] * S_LOG2E) : 0.f;
        acc[m][n] = (f32x4){0.f, 0.f, 0.f, 0.f};
      }
      rs0 = row_sum16(rs0); rs1 = row_sum16(rs1);
      rs2 = row_sum16(rs2); rs3 = row_sum16(rs3);
      if (lr == 0) {
        int row = m * 16 + lk * 4;
        rw[row + 0] += rs0; rw[row + 1] += rs1;
        rw[row + 2] += rs2; rw[row + 3] += rs3;
      }
    }
    Bw += 131072;   // next bc tile (16 colblks * 8 kc * 1024 B)
  }

  // ---- final: combine 4 wc-waves per row, one coalesced store ----
  __syncthreads();
  if (t < 256) {
    int half = t >> 7, r = t & 127;
    float sv = rsumAll[(half * 4 + 0) * 128 + r] + rsumAll[(half * 4 + 1) * 128 + r] +
               rsumAll[(half * 4 + 2) * 128 + r] + rsumAll[(half * 4 + 3) * 128 + r];
    partials[(size_t)cc * N_ROWS + (size_t)br * 256 + t] = sv;
  }
}

// ---------------- per-row loss + block partial sums ----------------
__global__ __launch_bounds__(256) void k_loss1(const float* __restrict__ partials,
                                               const float* __restrict__ tgt,
                                               float* __restrict__ bsum) {
  __shared__ float wsum[4];
  int i = blockIdx.x * 256 + threadIdx.x;
  const float* p = partials + i;
  float s = 0.f;
#pragma unroll
  for (int j = 0; j < NCB; ++j) s += p[(size_t)j * N_ROWS];
  float tl = tgt[i];
  float tcv = fminf(fmaxf(tl, -1.0f + 1e-7f), 1.0f - 1e-7f);
  const float cm = 0.95533648912560601964f;   // cos(0.3)
  const float sm = 0.29552020666133957510f;   // sin(0.3)
  float num = S_SCALE * (tcv * cm - sqrtf(fmaxf(1.0f - tcv * tcv, 0.f)) * sm);
  float sum_excl = s - __expf(S_SCALE * tl);
  float denom = __expf(num) + sum_excl;
  float L = num - __logf(denom);
#pragma unroll
  for (int m = 1; m < 64; m <<= 1) L += __shfl_xor(L, m, 64);
  int l = threadIdx.x & 63, w = threadIdx.x >> 6;
  if (l == 0) wsum[w] = L;
  __syncthreads();
  if (threadIdx.x == 0) bsum[blockIdx.x] = wsum[0] + wsum[1] + wsum[2] + wsum[3];
}

__global__ void k_loss2(const float* __restrict__ bsum, float* __restrict__ out) {
  float s = 0.f;
  for (int i = 0; i < 32; ++i) s += bsum[i];
  out[0] = -s / (float)N_ROWS;
}

// ---------------- launch ----------------
extern "C" void kernel_launch(void* const* d_in, const int* in_sizes, int n_in,
                              void* d_out, int out_size, void* d_ws, size_t ws_size,
                              hipStream_t stream) {
  const float* x = (const float*)d_in[0];
  const float* W = (const float*)d_in[1];
  const int* target = (const int*)d_in[2];
  float* out = (float*)d_out;
  char* ws = (char*)d_ws;

  unsigned short* xnb = (unsigned short*)(ws);              // 8192*256*2   = 4,194,304
  unsigned short* WbF = (unsigned short*)(ws + 4194304);    // 640*8*1024   = 5,242,880
  float* tgt = (float*)(ws + 9437184);                      // 8192*4
  float* partials = (float*)(ws + 9469952);                 // 8*8192*4     = 262,144
  float* bsum = (float*)(ws + 9732096);                     // 32*4

  k_normtgt<<<2048, 256, 0, stream>>>(x, W, target, xnb, tgt);
  k_convw<<<1280, 256, 0, stream>>>(W, WbF);
  k_gemm<<<256, 512, 0, stream>>>(xnb, WbF, partials);
  k_loss1<<<32, 256, 0, stream>>>(partials, tgt, bsum);
  k_loss2<<<1, 1, 0, stream>>>(bsum, out);
}